// Round 11
// baseline (62.705 us; speedup 1.0000x reference)
//
#include <hip/hip_runtime.h>

#define NCLS 256
#define NDF  512
#define BSZ  1024
#define ALP  0.1f

// score[b,c] = s1[b,c]-s1[b,t] + 0.5*ALP*(R[t,c]-R[t,t]),  t=gt[b]
// SINGLE DISPATCH, producer-consumer (no grid barrier):
//   bid<128  (producers): R slab partials, R9-validated path. Agent-scope
//            write-through stores to Rp, then RELEASE fetch_add(done).
//   bid>=128 (consumers): 32x32 s1 tile, full K=512 staged once + in-block
//            bias1 dot (reuses staged df regs) + 16 MFMA, THEN acquire-poll
//            done==128, fold 8 R slabs via agent loads, write out.
// Deadlock-safe: LDS 65.7KB -> 2 blocks/CU -> capacity 512 >= grid 384, all
// blocks co-resident under any dispatch order. Coherence = R5-validated
// flagged-ops pattern (no L2 maintenance instructions).
// MFMA mapping m89/m97-verified, r6-r10-validated (absmax 1.0).

typedef __attribute__((ext_vector_type(8))) short bf16x8;
typedef __attribute__((ext_vector_type(4))) float f32x4;

__device__ __forceinline__ unsigned rne_pk(float lo, float hi) {
    union { float f; unsigned u; } a, b;
    a.f = lo; b.f = hi;
    unsigned ua = (a.u + 0x7FFFu + ((a.u >> 16) & 1u)) >> 16;
    unsigned ub = (b.u + 0x7FFFu + ((b.u >> 16) & 1u)) & 0xFFFF0000u;
    return ua | ub;
}
__device__ __forceinline__ uint4 pk16(float4 p, float4 q) {
    uint4 r;
    r.x = rne_pk(p.x, p.y); r.y = rne_pk(p.z, p.w);
    r.z = rne_pk(q.x, q.y); r.w = rne_pk(q.z, q.w);
    return r;
}
__device__ __forceinline__ float bf16r(float x) {
    union { float f; unsigned u; } c; c.f = x;
    c.u = (c.u + 0x7FFFu + ((c.u >> 16) & 1u)) & 0xFFFF0000u;
    return c.f;
}
__device__ __forceinline__ void agent_store_f(float* p, float v) {
    __hip_atomic_store(p, v, __ATOMIC_RELAXED, __HIP_MEMORY_SCOPE_AGENT);
}
__device__ __forceinline__ float agent_load_f(const float* p) {
    return __hip_atomic_load(p, __ATOMIC_RELAXED, __HIP_MEMORY_SCOPE_AGENT);
}

// grid 384 x 256. bid<128: R producer. bid>=128: s1 consumer (sid=bid-128,
// bm=sid>>3 sample tile, bn=sid&7 col tile).
__global__ __launch_bounds__(256) void fused_pc(const float* __restrict__ df,
                                                const int* __restrict__ gt,
                                                const float* __restrict__ fc,
                                                float* __restrict__ Rp,
                                                unsigned int* __restrict__ done,
                                                float* __restrict__ out) {
    __shared__ union {
        struct { alignas(16) char A[32 * 1024]; alignas(16) char B[32 * 1024]; } s;  // s1: 32x512 bf16
        struct { alignas(16) char A[64 * 256]; alignas(16) char B[64 * 256]; } g;    // R: 64x128 bf16
        struct { int gts[BSZ]; unsigned long long bmap[64 * 16]; } r;                // R prepass
    } sm;
    __shared__ float biasL[32];

    const int tid = threadIdx.x;
    const int bid = blockIdx.x;
    const int lane = tid & 63;
    const int wv = tid >> 6;
    const int fr = lane & 15;
    const int fkb = (lane >> 4) * 16;
    const int fswz = (fr & 7) << 4;

    if (bid >= 128) {
        // =========================== s1 consumer ============================
        const int sid = bid - 128;
        const int bm = sid >> 3, bn = sid & 7;
        const int row = tid >> 3, kc = tid & 7, ln8 = tid & 7;

        const float* Ag = df + (bm * 32 + row) * NDF + kc * 64;
        const float* Bg = fc + (bn * 32 + row) * NDF + kc * 64;
        float4 a[16], b[16];
#pragma unroll
        for (int i = 0; i < 16; ++i) a[i] = ((const float4*)Ag)[i];
#pragma unroll
        for (int i = 0; i < 16; ++i) b[i] = ((const float4*)Bg)[i];
        const int swz = (row & 7) << 4;
        char* ar = sm.s.A + row * 1024;
        char* br = sm.s.B + row * 1024;
#pragma unroll
        for (int i = 0; i < 8; ++i)
            *(uint4*)(ar + ((kc * 128 + i * 16) ^ swz)) = pk16(a[2 * i], a[2 * i + 1]);
#pragma unroll
        for (int i = 0; i < 8; ++i)
            *(uint4*)(br + ((kc * 128 + i * 16) ^ swz)) = pk16(b[2 * i], b[2 * i + 1]);

        // bias dot: s1[b, t_b] over this thread's 64 dims, reusing a[] (df).
        // Same bf16 RNE rounding as the MFMA operands.
        const int trow = gt[bm * 32 + row];       // uniform across the 8-thread group
        const float* Tg = fc + trow * NDF + kc * 64;
        float s = 0.f;
#pragma unroll
        for (int i = 0; i < 16; ++i) {
            const float4 f = ((const float4*)Tg)[i];
            s = fmaf(bf16r(a[i].x), bf16r(f.x), s);
            s = fmaf(bf16r(a[i].y), bf16r(f.y), s);
            s = fmaf(bf16r(a[i].z), bf16r(f.z), s);
            s = fmaf(bf16r(a[i].w), bf16r(f.w), s);
        }
        s += __shfl_xor(s, 1); s += __shfl_xor(s, 2); s += __shfl_xor(s, 4);
        if (ln8 == 0) biasL[row] = s;
        __syncthreads();

        // MFMA: wave quadrant 16x16, 16 k-steps, 2 independent chains
        const int wm = (wv >> 1) * 16, wn = (wv & 1) * 16;
        f32x4 accE = 0.f, accO = 0.f;
#pragma unroll
        for (int st = 0; st < 16; st += 2) {
            const int kb0 = (st * 64 + fkb) ^ fswz;
            const int kb1 = ((st + 1) * 64 + fkb) ^ fswz;
            const bf16x8 aF0 = *(const bf16x8*)(sm.s.A + (wm + fr) * 1024 + kb0);
            const bf16x8 bF0 = *(const bf16x8*)(sm.s.B + (wn + fr) * 1024 + kb0);
            const bf16x8 aF1 = *(const bf16x8*)(sm.s.A + (wm + fr) * 1024 + kb1);
            const bf16x8 bF1 = *(const bf16x8*)(sm.s.B + (wn + fr) * 1024 + kb1);
            accE = __builtin_amdgcn_mfma_f32_16x16x32_bf16(aF0, bF0, accE, 0, 0, 0);
            accO = __builtin_amdgcn_mfma_f32_16x16x32_bf16(aF1, bF1, accO, 0, 0, 0);
        }

        // acquire-gate on the 128 producers (they run concurrently; near-zero spin)
        if (tid == 0) {
            while (__hip_atomic_load(done, __ATOMIC_ACQUIRE, __HIP_MEMORY_SCOPE_AGENT) < 128u)
                __builtin_amdgcn_s_sleep(2);
        }
        __syncthreads();

        // fused epilogue: fold 8 R slabs (agent loads bypass possibly-stale L2)
        const int colg = bn * 32 + wn + fr;
#pragma unroll
        for (int r = 0; r < 4; ++r) {
            const int lrow = wm + (lane >> 4) * 4 + r;
            const int bg = bm * 32 + lrow;
            const int t = gt[bg];
            float vR = 0.f, vtt = 0.f;
#pragma unroll
            for (int z = 0; z < 8; ++z) {
                const float* rp = Rp + z * (NCLS * NCLS) + t * NCLS;
                vR += agent_load_f(rp + colg);
                vtt += agent_load_f(rp + t);
            }
            out[bg * NCLS + colg] = (accE[r] + accO[r] - biasL[lrow])
                                    + 0.5f * ALP * (vR - vtt);
        }
        return;
    }

    // ============================ R producer ================================
    const int z = bid & 7;
    const int tile = bid >> 3;
    const int bm = tile & 3, bn = tile >> 2;
    const int D0 = z * 64;
    const int sr = tid >> 2;
    const int sswz = (sr & 7) << 4;
    const int clocal = sr;
    const int myclass = bm * 64 + clocal;
    const int dim0 = D0 + (tid & 3) * 16;
    const int kbl = (tid & 3) * 32;
    const int kbq = 128 + kbl;
    char* arow = sm.g.A + sr * 256;
    char* brow = sm.g.B + sr * 256;

    const float* Bg = fc + (bn * 64 + sr) * NDF + dim0;
    const float4 b0 = ((const float4*)Bg)[0], b1 = ((const float4*)Bg)[1],
                 b2 = ((const float4*)Bg)[2], b3 = ((const float4*)Bg)[3];

    for (int i = tid; i < BSZ; i += 256) sm.r.gts[i] = gt[i];
    for (int i = tid; i < 1024; i += 256) sm.r.bmap[i] = 0ull;
    __syncthreads();
    for (int i = tid; i < BSZ; i += 256) {
        const int c = sm.r.gts[i] - bm * 64;
        if ((unsigned)c < 64u) atomicOr(&sm.r.bmap[c * 16 + (i >> 6)], 1ull << (i & 63));
    }
    const float* fct = fc + myclass * NDF + dim0;
    float fcq[16];
    {
        const float4 q0 = ((const float4*)fct)[0], q1 = ((const float4*)fct)[1];
        const float4 q2 = ((const float4*)fct)[2], q3 = ((const float4*)fct)[3];
        fcq[0]=q0.x; fcq[1]=q0.y; fcq[2]=q0.z; fcq[3]=q0.w;
        fcq[4]=q1.x; fcq[5]=q1.y; fcq[6]=q1.z; fcq[7]=q1.w;
        fcq[8]=q2.x; fcq[9]=q2.y; fcq[10]=q2.z; fcq[11]=q2.w;
        fcq[12]=q3.x; fcq[13]=q3.y; fcq[14]=q3.z; fcq[15]=q3.w;
    }
    __syncthreads();

    // sequential running-var recurrence for (myclass, dims dim0..dim0+16)
    float m[16], v[16];
#pragma unroll
    for (int j = 0; j < 16; ++j) { m[j] = 0.f; v[j] = 0.f; }
    float nf = 0.f;
    {
        int w = 0;
        unsigned long long bits = sm.r.bmap[clocal * 16];
        auto next = [&]() -> int {
            while (bits == 0ull) {
                if (w >= 15) return -1;
                bits = sm.r.bmap[clocal * 16 + (++w)];
            }
            const int b = __ffsll((unsigned long long)bits) - 1;
            bits &= bits - 1ull;
            return (w << 6) + b;
        };
        int cur = next();
        float f[16];
        if (cur >= 0) {
            const float* p = df + cur * NDF + dim0;
            const float4 q0 = ((const float4*)p)[0], q1 = ((const float4*)p)[1];
            const float4 q2 = ((const float4*)p)[2], q3 = ((const float4*)p)[3];
            f[0]=q0.x; f[1]=q0.y; f[2]=q0.z; f[3]=q0.w;
            f[4]=q1.x; f[5]=q1.y; f[6]=q1.z; f[7]=q1.w;
            f[8]=q2.x; f[9]=q2.y; f[10]=q2.z; f[11]=q2.w;
            f[12]=q3.x; f[13]=q3.y; f[14]=q3.z; f[15]=q3.w;
        }
        while (cur >= 0) {
            const int nxt = next();
            float g[16];
            if (nxt >= 0) {   // prefetch next sample before the dependent update
                const float* p = df + nxt * NDF + dim0;
                const float4 q0 = ((const float4*)p)[0], q1 = ((const float4*)p)[1];
                const float4 q2 = ((const float4*)p)[2], q3 = ((const float4*)p)[3];
                g[0]=q0.x; g[1]=q0.y; g[2]=q0.z; g[3]=q0.w;
                g[4]=q1.x; g[5]=q1.y; g[6]=q1.z; g[7]=q1.w;
                g[8]=q2.x; g[9]=q2.y; g[10]=q2.z; g[11]=q2.w;
                g[12]=q3.x; g[13]=q3.y; g[14]=q3.z; g[15]=q3.w;
            }
            const float c2 = 1.0f / (nf + 1.0f);
            const float c1 = nf * c2;
            const float c12 = c1 * c2;
#pragma unroll
            for (int j = 0; j < 16; ++j) {
                m[j] = m[j] * c1 + f[j] * c2;     // == f when nf==0
                const float a = f[j] - m[j];
                v[j] = v[j] * c1 + a * a * c12;
            }
            nf += 1.0f;
#pragma unroll
            for (int j = 0; j < 16; ++j) f[j] = g[j];
            cur = nxt;
        }
    }
    __syncthreads();   // bmap reads done before staging overwrites (LDS union!)

    // single staging round: linear cols (A=-2*fc_t*var, B=fc) | quad (A=var, B=fc^2)
    {
        float4 l0, l1, l2, l3;
        l0.x=-2.f*fcq[0]*v[0];  l0.y=-2.f*fcq[1]*v[1];  l0.z=-2.f*fcq[2]*v[2];  l0.w=-2.f*fcq[3]*v[3];
        l1.x=-2.f*fcq[4]*v[4];  l1.y=-2.f*fcq[5]*v[5];  l1.z=-2.f*fcq[6]*v[6];  l1.w=-2.f*fcq[7]*v[7];
        l2.x=-2.f*fcq[8]*v[8];  l2.y=-2.f*fcq[9]*v[9];  l2.z=-2.f*fcq[10]*v[10]; l2.w=-2.f*fcq[11]*v[11];
        l3.x=-2.f*fcq[12]*v[12]; l3.y=-2.f*fcq[13]*v[13]; l3.z=-2.f*fcq[14]*v[14]; l3.w=-2.f*fcq[15]*v[15];
        float4 p0, p1, p2, p3;
        p0.x=v[0];  p0.y=v[1];  p0.z=v[2];  p0.w=v[3];
        p1.x=v[4];  p1.y=v[5];  p1.z=v[6];  p1.w=v[7];
        p2.x=v[8];  p2.y=v[9];  p2.z=v[10]; p2.w=v[11];
        p3.x=v[12]; p3.y=v[13]; p3.z=v[14]; p3.w=v[15];
        float4 s0, s1, s2, s3;
        s0.x=b0.x*b0.x; s0.y=b0.y*b0.y; s0.z=b0.z*b0.z; s0.w=b0.w*b0.w;
        s1.x=b1.x*b1.x; s1.y=b1.y*b1.y; s1.z=b1.z*b1.z; s1.w=b1.w*b1.w;
        s2.x=b2.x*b2.x; s2.y=b2.y*b2.y; s2.z=b2.z*b2.z; s2.w=b2.w*b2.w;
        s3.x=b3.x*b3.x; s3.y=b3.y*b3.y; s3.z=b3.z*b3.z; s3.w=b3.w*b3.w;
        *(uint4*)(arow + ((kbl + 0) ^ sswz)) = pk16(l0, l1);
        *(uint4*)(arow + ((kbl + 16) ^ sswz)) = pk16(l2, l3);
        *(uint4*)(arow + ((kbq + 0) ^ sswz)) = pk16(p0, p1);
        *(uint4*)(arow + ((kbq + 16) ^ sswz)) = pk16(p2, p3);
        *(uint4*)(brow + ((kbl + 0) ^ sswz)) = pk16(b0, b1);
        *(uint4*)(brow + ((kbl + 16) ^ sswz)) = pk16(b2, b3);
        *(uint4*)(brow + ((kbq + 0) ^ sswz)) = pk16(s0, s1);
        *(uint4*)(brow + ((kbq + 16) ^ sswz)) = pk16(s2, s3);
    }
    __syncthreads();

    const int wm = (wv >> 1) * 32, wn = (wv & 1) * 32;
    f32x4 acc[2][2];
    acc[0][0] = 0.f; acc[0][1] = 0.f; acc[1][0] = 0.f; acc[1][1] = 0.f;
#pragma unroll
    for (int st = 0; st < 4; ++st) {
        const int kb = (st * 64 + fkb) ^ fswz;
        const bf16x8 aF0 = *(const bf16x8*)(sm.g.A + (wm + fr) * 256 + kb);
        const bf16x8 aF1 = *(const bf16x8*)(sm.g.A + (wm + 16 + fr) * 256 + kb);
        const bf16x8 bF0 = *(const bf16x8*)(sm.g.B + (wn + fr) * 256 + kb);
        const bf16x8 bF1 = *(const bf16x8*)(sm.g.B + (wn + 16 + fr) * 256 + kb);
        acc[0][0] = __builtin_amdgcn_mfma_f32_16x16x32_bf16(aF0, bF0, acc[0][0], 0, 0, 0);
        acc[0][1] = __builtin_amdgcn_mfma_f32_16x16x32_bf16(aF0, bF1, acc[0][1], 0, 0, 0);
        acc[1][0] = __builtin_amdgcn_mfma_f32_16x16x32_bf16(aF1, bF0, acc[1][0], 0, 0, 0);
        acc[1][1] = __builtin_amdgcn_mfma_f32_16x16x32_bf16(aF1, bF1, acc[1][1], 0, 0, 0);
    }

    // agent write-through stores (coherent at MALL; no L2 maintenance)
    float* base = Rp + z * (NCLS * NCLS) + (bm * 64) * NCLS + bn * 64;
#pragma unroll
    for (int mi = 0; mi < 2; ++mi)
#pragma unroll
        for (int ni = 0; ni < 2; ++ni)
#pragma unroll
            for (int r2 = 0; r2 < 4; ++r2)
                agent_store_f(base + (wm + mi * 16 + (lane >> 4) * 4 + r2) * NCLS
                                   + wn + ni * 16 + fr, acc[mi][ni][r2]);
    __syncthreads();   // all block stores drained (vmcnt(0) before barrier)
    if (tid == 0)
        __hip_atomic_fetch_add(done, 1u, __ATOMIC_RELEASE, __HIP_MEMORY_SCOPE_AGENT);
}

// ---------------------------------------------------------------------------
extern "C" void kernel_launch(void* const* d_in, const int* in_sizes, int n_in,
                              void* d_out, int out_size, void* d_ws, size_t ws_size,
                              hipStream_t stream) {
    const float* df = (const float*)d_in[0];
    const int* gt = (const int*)d_in[1];
    const float* fc = (const float*)d_in[2];
    float* out = (float*)d_out;

    float* ws = (float*)d_ws;
    float* Rp = ws;                                  // 8*NCLS*NCLS = 2 MB
    unsigned int* done = (unsigned int*)(Rp + 8 * NCLS * NCLS);

    hipMemsetAsync(done, 0, sizeof(unsigned int), stream);   // reset gate
    fused_pc<<<384, 256, 0, stream>>>(df, gt, fc, Rp, done, out);
}

// Round 12
// 25.340 us; speedup vs baseline: 2.4745x; 2.4745x over previous
//
#include <hip/hip_runtime.h>

#define NCLS 256
#define NDF  512
#define BSZ  1024
#define ALP  0.1f

// score[b,c] = s1[b,c]-s1[b,t] + 0.5*ALP*(R[t,c]-R[t,t]),  t=gt[b]
// Two dispatches (kernel boundary = the only cheap cross-XCD fence on this
// chip; R4/R5/R10/R11 all showed in-kernel cross-block sync costs 2-5x).
// R12 = R9 math with occupancy fixes (R10/R11 counters: 1 wave/SIMD exposed
// every latency):
//   k1 (128 blk x 512 thr): waves 0-3 = R slab partials (R9-validated path,
//       tid<256 indexing unchanged); waves 4-7 = bias1 dots co-scheduled with
//       the recurrence's gather stalls (8 samples/block).
//   k2 (256 blk x 512 thr): 32x32 s1 tile, 8 waves split K (h=0/1), fold via
//       reused tile LDS, epilogue rows split 2/wave (half the slab-fold work
//       per lane), writes out directly.
// MFMA mapping m89/m97-verified, r6-r11-validated (absmax 1.0).

typedef __attribute__((ext_vector_type(8))) short bf16x8;
typedef __attribute__((ext_vector_type(4))) float f32x4;

__device__ __forceinline__ unsigned rne_pk(float lo, float hi) {
    union { float f; unsigned u; } a, b;
    a.f = lo; b.f = hi;
    unsigned ua = (a.u + 0x7FFFu + ((a.u >> 16) & 1u)) >> 16;
    unsigned ub = (b.u + 0x7FFFu + ((b.u >> 16) & 1u)) & 0xFFFF0000u;
    return ua | ub;
}
__device__ __forceinline__ uint4 pk16(float4 p, float4 q) {
    uint4 r;
    r.x = rne_pk(p.x, p.y); r.y = rne_pk(p.z, p.w);
    r.z = rne_pk(q.x, q.y); r.w = rne_pk(q.z, q.w);
    return r;
}
__device__ __forceinline__ float bf16r(float x) {
    union { float f; unsigned u; } c; c.f = x;
    c.u = (c.u + 0x7FFFu + ((c.u >> 16) & 1u)) & 0xFFFF0000u;
    return c.f;
}

// ---------------------------------------------------------------------------
// Kernel 1: 128 blocks x 512 threads.
//  waves 0-3 (tid<256): R slab partial, mapping identical to R9:
//    z=bid&7 (64-dim chunk), tile=bid>>3: bm=tile&3, bn=tile>>2.
//  waves 4-7: bias1[bid*8 + (wv-4)*2 + (lane>>5)] = bf16-rounded dot(df_b, fc_t).
__global__ __launch_bounds__(512) void k1_R_bias(const float* __restrict__ df,
                                                 const int* __restrict__ gt,
                                                 const float* __restrict__ fc,
                                                 float* __restrict__ Rp,
                                                 float* __restrict__ bias1) {
    __shared__ union {
        struct { alignas(16) char A[64 * 256]; alignas(16) char B[64 * 256]; } g;  // 64x128 bf16
        struct { int gts[BSZ]; unsigned long long bmap[64 * 16]; } r;
    } sm;

    const int tid = threadIdx.x;
    const int bid = blockIdx.x;
    const int lane = tid & 63;
    const int wv = tid >> 6;

    // ---- prepass: all 512 threads stage gt + zero bitmap ----
    for (int i = tid; i < BSZ; i += 512) sm.r.gts[i] = gt[i];
    for (int i = tid; i < 1024; i += 512) sm.r.bmap[i] = 0ull;
    __syncthreads();                                   // S1
    for (int i = tid; i < BSZ; i += 512) {
        const int c = sm.r.gts[i] - ((bid >> 3) & 3) * 64;
        if ((unsigned)c < 64u) atomicOr(&sm.r.bmap[c * 16 + (i >> 6)], 1ull << (i & 63));
    }

    // R-wave setup (tid<256): identical indexing to R9
    const int z = bid & 7;
    const int tile = bid >> 3;
    const int bm = tile & 3, bn = tile >> 2;
    const int D0 = z * 64;
    const int sr = tid >> 2;                 // valid for tid<256
    const int sswz = (sr & 7) << 4;
    const int clocal = sr;
    const int myclass = bm * 64 + (clocal & 63);
    const int dim0 = D0 + (tid & 3) * 16;
    const int kbl = (tid & 3) * 32;
    const int kbq = 128 + kbl;

    float fcq[16];
    float4 b0, b1, b2, b3;
    int bsample = 0, bt = 0;
    if (wv < 4) {
        const float* Bg = fc + (bn * 64 + sr) * NDF + dim0;
        b0 = ((const float4*)Bg)[0]; b1 = ((const float4*)Bg)[1];
        b2 = ((const float4*)Bg)[2]; b3 = ((const float4*)Bg)[3];
        const float* fct = fc + myclass * NDF + dim0;
        const float4 q0 = ((const float4*)fct)[0], q1 = ((const float4*)fct)[1];
        const float4 q2 = ((const float4*)fct)[2], q3 = ((const float4*)fct)[3];
        fcq[0]=q0.x; fcq[1]=q0.y; fcq[2]=q0.z; fcq[3]=q0.w;
        fcq[4]=q1.x; fcq[5]=q1.y; fcq[6]=q1.z; fcq[7]=q1.w;
        fcq[8]=q2.x; fcq[9]=q2.y; fcq[10]=q2.z; fcq[11]=q2.w;
        fcq[12]=q3.x; fcq[13]=q3.y; fcq[14]=q3.z; fcq[15]=q3.w;
    } else {
        bsample = bid * 8 + (wv - 4) * 2 + (lane >> 5);
        bt = sm.r.gts[bsample];              // gts valid (staged before S1)
    }
    __syncthreads();                                   // S2 (bmap atomics done)

    float m[16], v[16];
    if (wv < 4) {
        // ---- sequential running-var recurrence (myclass, 16 dims) ----
#pragma unroll
        for (int j = 0; j < 16; ++j) { m[j] = 0.f; v[j] = 0.f; }
        float nf = 0.f;
        int w = 0;
        unsigned long long bits = sm.r.bmap[clocal * 16];
        auto next = [&]() -> int {
            while (bits == 0ull) {
                if (w >= 15) return -1;
                bits = sm.r.bmap[clocal * 16 + (++w)];
            }
            const int b = __ffsll((unsigned long long)bits) - 1;
            bits &= bits - 1ull;
            return (w << 6) + b;
        };
        int cur = next();
        float f[16];
        if (cur >= 0) {
            const float* p = df + cur * NDF + dim0;
            const float4 q0 = ((const float4*)p)[0], q1 = ((const float4*)p)[1];
            const float4 q2 = ((const float4*)p)[2], q3 = ((const float4*)p)[3];
            f[0]=q0.x; f[1]=q0.y; f[2]=q0.z; f[3]=q0.w;
            f[4]=q1.x; f[5]=q1.y; f[6]=q1.z; f[7]=q1.w;
            f[8]=q2.x; f[9]=q2.y; f[10]=q2.z; f[11]=q2.w;
            f[12]=q3.x; f[13]=q3.y; f[14]=q3.z; f[15]=q3.w;
        }
        while (cur >= 0) {
            const int nxt = next();
            float g[16];
            if (nxt >= 0) {   // prefetch next sample before the dependent update
                const float* p = df + nxt * NDF + dim0;
                const float4 q0 = ((const float4*)p)[0], q1 = ((const float4*)p)[1];
                const float4 q2 = ((const float4*)p)[2], q3 = ((const float4*)p)[3];
                g[0]=q0.x; g[1]=q0.y; g[2]=q0.z; g[3]=q0.w;
                g[4]=q1.x; g[5]=q1.y; g[6]=q1.z; g[7]=q1.w;
                g[8]=q2.x; g[9]=q2.y; g[10]=q2.z; g[11]=q2.w;
                g[12]=q3.x; g[13]=q3.y; g[14]=q3.z; g[15]=q3.w;
            }
            const float c2 = 1.0f / (nf + 1.0f);
            const float c1 = nf * c2;
            const float c12 = c1 * c2;
#pragma unroll
            for (int j = 0; j < 16; ++j) {
                m[j] = m[j] * c1 + f[j] * c2;     // == f when nf==0
                const float a = f[j] - m[j];
                v[j] = v[j] * c1 + a * a * c12;
            }
            nf += 1.0f;
#pragma unroll
            for (int j = 0; j < 16; ++j) f[j] = g[j];
            cur = nxt;
        }
    } else {
        // ---- bias dot, co-scheduled with the recurrence's gather stalls ----
        const int l32 = lane & 31;
        const float* pd = df + bsample * NDF + l32 * 16;
        const float* pf = fc + bt * NDF + l32 * 16;
        float s = 0.f;
#pragma unroll
        for (int i = 0; i < 4; ++i) {
            const float4 dq = ((const float4*)pd)[i];
            const float4 fq = ((const float4*)pf)[i];
            s = fmaf(bf16r(dq.x), bf16r(fq.x), s);
            s = fmaf(bf16r(dq.y), bf16r(fq.y), s);
            s = fmaf(bf16r(dq.z), bf16r(fq.z), s);
            s = fmaf(bf16r(dq.w), bf16r(fq.w), s);
        }
        s += __shfl_xor(s, 1); s += __shfl_xor(s, 2); s += __shfl_xor(s, 4);
        s += __shfl_xor(s, 8); s += __shfl_xor(s, 16);
        if (l32 == 0) bias1[bsample] = s;
    }
    __syncthreads();                                   // S3 (bmap dead after)

    if (wv < 4) {
        // ---- staging: linear cols (A=-2*fc_t*var, B=fc) | quad (A=var, B=fc^2) ----
        char* arow = sm.g.A + sr * 256;
        char* brow = sm.g.B + sr * 256;
        float4 l0, l1, l2, l3;
        l0.x=-2.f*fcq[0]*v[0];  l0.y=-2.f*fcq[1]*v[1];  l0.z=-2.f*fcq[2]*v[2];  l0.w=-2.f*fcq[3]*v[3];
        l1.x=-2.f*fcq[4]*v[4];  l1.y=-2.f*fcq[5]*v[5];  l1.z=-2.f*fcq[6]*v[6];  l1.w=-2.f*fcq[7]*v[7];
        l2.x=-2.f*fcq[8]*v[8];  l2.y=-2.f*fcq[9]*v[9];  l2.z=-2.f*fcq[10]*v[10]; l2.w=-2.f*fcq[11]*v[11];
        l3.x=-2.f*fcq[12]*v[12]; l3.y=-2.f*fcq[13]*v[13]; l3.z=-2.f*fcq[14]*v[14]; l3.w=-2.f*fcq[15]*v[15];
        float4 p0, p1, p2, p3;
        p0.x=v[0];  p0.y=v[1];  p0.z=v[2];  p0.w=v[3];
        p1.x=v[4];  p1.y=v[5];  p1.z=v[6];  p1.w=v[7];
        p2.x=v[8];  p2.y=v[9];  p2.z=v[10]; p2.w=v[11];
        p3.x=v[12]; p3.y=v[13]; p3.z=v[14]; p3.w=v[15];
        float4 s0, s1, s2, s3;
        s0.x=b0.x*b0.x; s0.y=b0.y*b0.y; s0.z=b0.z*b0.z; s0.w=b0.w*b0.w;
        s1.x=b1.x*b1.x; s1.y=b1.y*b1.y; s1.z=b1.z*b1.z; s1.w=b1.w*b1.w;
        s2.x=b2.x*b2.x; s2.y=b2.y*b2.y; s2.z=b2.z*b2.z; s2.w=b2.w*b2.w;
        s3.x=b3.x*b3.x; s3.y=b3.y*b3.y; s3.z=b3.z*b3.z; s3.w=b3.w*b3.w;
        *(uint4*)(arow + ((kbl + 0) ^ sswz)) = pk16(l0, l1);
        *(uint4*)(arow + ((kbl + 16) ^ sswz)) = pk16(l2, l3);
        *(uint4*)(arow + ((kbq + 0) ^ sswz)) = pk16(p0, p1);
        *(uint4*)(arow + ((kbq + 16) ^ sswz)) = pk16(p2, p3);
        *(uint4*)(brow + ((kbl + 0) ^ sswz)) = pk16(b0, b1);
        *(uint4*)(brow + ((kbl + 16) ^ sswz)) = pk16(b2, b3);
        *(uint4*)(brow + ((kbq + 0) ^ sswz)) = pk16(s0, s1);
        *(uint4*)(brow + ((kbq + 16) ^ sswz)) = pk16(s2, s3);
    }
    __syncthreads();                                   // S4

    if (wv < 4) {
        const int fr = lane & 15;
        const int fkb = (lane >> 4) * 16;
        const int fswz = (fr & 7) << 4;
        const int wm = (wv >> 1) * 32, wn = (wv & 1) * 32;
        f32x4 acc[2][2];
        acc[0][0] = 0.f; acc[0][1] = 0.f; acc[1][0] = 0.f; acc[1][1] = 0.f;
#pragma unroll
        for (int st = 0; st < 4; ++st) {
            const int kb = (st * 64 + fkb) ^ fswz;
            const bf16x8 aF0 = *(const bf16x8*)(sm.g.A + (wm + fr) * 256 + kb);
            const bf16x8 aF1 = *(const bf16x8*)(sm.g.A + (wm + 16 + fr) * 256 + kb);
            const bf16x8 bF0 = *(const bf16x8*)(sm.g.B + (wn + fr) * 256 + kb);
            const bf16x8 bF1 = *(const bf16x8*)(sm.g.B + (wn + 16 + fr) * 256 + kb);
            acc[0][0] = __builtin_amdgcn_mfma_f32_16x16x32_bf16(aF0, bF0, acc[0][0], 0, 0, 0);
            acc[0][1] = __builtin_amdgcn_mfma_f32_16x16x32_bf16(aF0, bF1, acc[0][1], 0, 0, 0);
            acc[1][0] = __builtin_amdgcn_mfma_f32_16x16x32_bf16(aF1, bF0, acc[1][0], 0, 0, 0);
            acc[1][1] = __builtin_amdgcn_mfma_f32_16x16x32_bf16(aF1, bF1, acc[1][1], 0, 0, 0);
        }
        float* base = Rp + z * (NCLS * NCLS) + (bm * 64) * NCLS + bn * 64;
#pragma unroll
        for (int mi = 0; mi < 2; ++mi)
#pragma unroll
            for (int ni = 0; ni < 2; ++ni)
#pragma unroll
                for (int r2 = 0; r2 < 4; ++r2)
                    base[(wm + mi * 16 + (lane >> 4) * 4 + r2) * NCLS + wn + ni * 16 + fr] =
                        acc[mi][ni][r2];
    }
}

// ---------------------------------------------------------------------------
// Kernel 2: 256 blocks x 512 threads. Block (bm=bid>>3, bn=bid&7): 32x32 out
// tile, full K=512 staged once. 8 waves: quadrant q=wv&3, K-half h=wv>>2.
// Fold partials via reused tile LDS; epilogue rows split 2 per wave.
__global__ __launch_bounds__(512) void k2_s1_out(const float* __restrict__ df,
                                                 const int* __restrict__ gt,
                                                 const float* __restrict__ fc,
                                                 const float* __restrict__ Rp,
                                                 const float* __restrict__ bias1,
                                                 float* __restrict__ out) {
    __shared__ union {
        struct { alignas(16) char A[32 * 1024]; alignas(16) char B[32 * 1024]; } t;
        float fold[8 * 256];                            // aliases A (tiles dead)
    } sm;

    const int tid = threadIdx.x;
    const int bn = blockIdx.x & 7, bm = blockIdx.x >> 3;
    const int lane = tid & 63, wv = tid >> 6;

    // ---- staging: row = tid>>4 (0..31), seg = tid&15 -> 32 floats (8 float4) ----
    const int row = tid >> 4, seg = tid & 15;
    const float* Ag = df + (bm * 32 + row) * NDF + seg * 32;
    const float* Bg = fc + (bn * 32 + row) * NDF + seg * 32;
    float4 a[8], b[8];
#pragma unroll
    for (int i = 0; i < 8; ++i) a[i] = ((const float4*)Ag)[i];
#pragma unroll
    for (int i = 0; i < 8; ++i) b[i] = ((const float4*)Bg)[i];
    const int swz = (row & 7) << 4;
    char* ar = sm.t.A + row * 1024;
    char* br = sm.t.B + row * 1024;
#pragma unroll
    for (int j = 0; j < 4; ++j)
        *(uint4*)(ar + ((seg * 64 + j * 16) ^ swz)) = pk16(a[2 * j], a[2 * j + 1]);
#pragma unroll
    for (int j = 0; j < 4; ++j)
        *(uint4*)(br + ((seg * 64 + j * 16) ^ swz)) = pk16(b[2 * j], b[2 * j + 1]);
    __syncthreads();

    // ---- MFMA: quadrant (wm,wn), K-half h -> 8 k-steps ----
    const int q = wv & 3, h = wv >> 2;
    const int wm = (q >> 1) * 16, wn = (q & 1) * 16;
    const int fr = lane & 15;
    const int fkb = (lane >> 4) * 16;
    const int fswz = (fr & 7) << 4;
    f32x4 acc = 0.f;
#pragma unroll
    for (int s = 0; s < 8; ++s) {
        const int kb = ((h * 8 + s) * 64 + fkb) ^ fswz;
        const bf16x8 aF = *(const bf16x8*)(sm.t.A + (wm + fr) * 1024 + kb);
        const bf16x8 bF = *(const bf16x8*)(sm.t.B + (wn + fr) * 1024 + kb);
        acc = __builtin_amdgcn_mfma_f32_16x16x32_bf16(aF, bF, acc, 0, 0, 0);
    }
    __syncthreads();                     // tile reads done; LDS reusable as fold
    ((f32x4*)sm.fold)[wv * 64 + lane] = acc;
    __syncthreads();
    const f32x4 other = ((f32x4*)sm.fold)[(wv ^ 4) * 64 + lane];
    acc += other;                        // both K-half waves now hold full s1

    // ---- fused epilogue: this wave handles rows r = h*2, h*2+1 ----
    const int colg = bn * 32 + wn + fr;
#pragma unroll
    for (int rr = 0; rr < 2; ++rr) {
        const float av = h ? ((rr == 0) ? acc[2] : acc[3])
                           : ((rr == 0) ? acc[0] : acc[1]);   // static indices
        const int r = h * 2 + rr;
        const int bg = bm * 32 + wm + (lane >> 4) * 4 + r;
        const int t = gt[bg];
        float vR = 0.f, vtt = 0.f;
#pragma unroll
        for (int z = 0; z < 8; ++z) {
            const float* rp = Rp + z * (NCLS * NCLS) + t * NCLS;
            vR += rp[colg];
            vtt += rp[t];
        }
        out[bg * NCLS + colg] = (av - bias1[bg]) + 0.5f * ALP * (vR - vtt);
    }
}

// ---------------------------------------------------------------------------
extern "C" void kernel_launch(void* const* d_in, const int* in_sizes, int n_in,
                              void* d_out, int out_size, void* d_ws, size_t ws_size,
                              hipStream_t stream) {
    const float* df = (const float*)d_in[0];
    const int* gt = (const int*)d_in[1];
    const float* fc = (const float*)d_in[2];
    float* out = (float*)d_out;

    float* ws = (float*)d_ws;
    float* Rp = ws;                            // 8*NCLS*NCLS = 524,288 f (2 MB)
    float* bias1 = Rp + 8 * NCLS * NCLS;       // 1024 f

    k1_R_bias<<<128, 512, 0, stream>>>(df, gt, fc, Rp, bias1);
    k2_s1_out<<<256, 512, 0, stream>>>(df, gt, fc, Rp, bias1, out);
}